// Round 6
// baseline (343.852 us; speedup 1.0000x reference)
//
#include <hip/hip_runtime.h>

// LIF neuron scan: 16384 neurons x 2048 sequential steps; 64 neurons/block,
// 256 blocks = 1 block/CU. R6 = producer/consumer LDS ring, fixed:
//  - NO acquire atomics (R5's consumer acquire-polls forced vmcnt(0) drains
//    of its own output stores every chunk -> 2650cyc/chunk ring stall).
//    All handshakes: relaxed LDS atomics + asm barriers + lgkmcnt(0) only.
//  - Producers load float4 (1KB/VMEM instr, m13-style): 8 instr/chunk,
//    7 producers x 8KB in flight = ~56KB/CU >> Little's-law need.
// Consumer wave 0 carries the serial V/Vth chain; its vmcnt stream holds
// only output stores and is never waited.
//
// Exactness (binary spike output): contract(off), reference op order:
//   V = (V + 0.05f*(I-V)) + nz ; s = V>=Vth ; V = s?0:V ;
//   Vth = s ? min(max(Vth+0.1f,0.5f),2.0f) : Vth

constexpr int N  = 16384;   // neurons
constexpr int T  = 2048;    // sequential steps
constexpr int U  = 16;      // timesteps per chunk
constexpr int NC = T / U;   // 128 chunks
constexpr int S  = 16;      // LDS ring slots (pow2) -> 16 x 8KB = 128KB
constexpr int NP = 7;       // producer waves

__global__
__attribute__((amdgpu_flat_work_group_size(512, 512)))
void TorchLIFNeuronGroup_85152021610615_kernel(const float* __restrict__ I,
                                               const float* __restrict__ Z,
                                               float* __restrict__ O) {
    #pragma clang fp contract(off)
    __shared__ float ringI[S][U][64];     // [slot][timestep][neuron lane]
    __shared__ float ringZ[S][U][64];
    __shared__ int   flags[NC];           // chunk k landed in LDS
    __shared__ int   cons;                // highest chunk consumed

    if (threadIdx.x < NC) flags[threadIdx.x] = 0;
    if (threadIdx.x == 0) cons = -1;
    __syncthreads();

    const int wave = threadIdx.x >> 6;
    const int lane = threadIdx.x & 63;

    if (wave != 0) {
        // ---------------- producer waves 1..7 ----------------
        const int p = wave - 1;
        const int r = lane >> 4;          // row-in-quad 0..3
        const int c = lane & 15;          // col group 0..15 (16B each)
        const float* bI = I + (size_t)blockIdx.x * 64 + 4 * c;
        const float* bZ = Z + (size_t)blockIdx.x * 64 + 4 * c;

        for (int k = p; k < NC; k += NP) {
            const int    slot = k & (S - 1);
            const size_t row0 = (size_t)k * U + r;
            // 8 x dwordx4: rows 16k + {0..15}, 1KB per instruction
            float4 vi[4], vz[4];
            #pragma unroll
            for (int i = 0; i < 4; ++i) {
                vi[i] = *(const float4*)(bI + (row0 + 4u * i) * N);
                vz[i] = *(const float4*)(bZ + (row0 + 4u * i) * N);
            }
            __builtin_amdgcn_sched_barrier(0);   // keep loads issued above poll
            // slot backpressure (relaxed, LDS-only)
            while (__hip_atomic_load(&cons, __ATOMIC_RELAXED,
                                     __HIP_MEMORY_SCOPE_WORKGROUP) < k - S)
                __builtin_amdgcn_s_sleep(1);
            __asm__ volatile("" ::: "memory");
            #pragma unroll
            for (int i = 0; i < 4; ++i) {
                *(float4*)&ringI[slot][4 * i + r][4 * c] = vi[i];
                *(float4*)&ringZ[slot][4 * i + r][4 * c] = vz[i];
            }
            __asm__ volatile("s_waitcnt lgkmcnt(0)" ::: "memory");  // writes in LDS
            if (lane == 0)
                __hip_atomic_store(&flags[k], 1, __ATOMIC_RELAXED,
                                   __HIP_MEMORY_SCOPE_WORKGROUP);
        }

    } else {
        // ---------------- consumer wave 0 ----------------
        float* op = O + (size_t)blockIdx.x * 64 + lane;
        float V   = 0.0f;   // V_RESET
        float Vth = 1.0f;   // V_TH0
        float ai[U], az[U], bi[U], bz[U];

        // prologue: chunk 0 -> a
        while (__hip_atomic_load(&flags[0], __ATOMIC_RELAXED,
                                 __HIP_MEMORY_SCOPE_WORKGROUP) == 0)
            __builtin_amdgcn_s_sleep(1);
        __asm__ volatile("" ::: "memory");
        #pragma unroll
        for (int u = 0; u < U; ++u) { ai[u] = ringI[0][u][lane]; az[u] = ringZ[0][u][lane]; }

        for (int k = 0; k < NC; k += 2) {
            // prefetch chunk k+1 -> b (NC even)
            while (__hip_atomic_load(&flags[k + 1], __ATOMIC_RELAXED,
                                     __HIP_MEMORY_SCOPE_WORKGROUP) == 0)
                __builtin_amdgcn_s_sleep(1);
            __asm__ volatile("" ::: "memory");
            {
                const int slot = (k + 1) & (S - 1);
                #pragma unroll
                for (int u = 0; u < U; ++u) { bi[u] = ringI[slot][u][lane]; bz[u] = ringZ[slot][u][lane]; }
            }
            // compute chunk k from a (stores never waited)
            #pragma unroll
            for (int u = 0; u < U; ++u) {
                #pragma clang fp contract(off)
                float d  = ai[u] - V;
                float v1 = V + 0.05f * d;           // DT/TAU
                float v2 = v1 + az[u];
                bool  s  = (v2 >= Vth);
                V = s ? 0.0f : v2;
                float nth = fminf(fmaxf(Vth + 0.1f, 0.5f), 2.0f);
                Vth = s ? nth : Vth;
                op[(size_t)(k * U + u) * N] = s ? 1.0f : 0.0f;
            }
            // prefetch chunk k+2 -> a
            if (k + 2 < NC) {
                while (__hip_atomic_load(&flags[k + 2], __ATOMIC_RELAXED,
                                         __HIP_MEMORY_SCOPE_WORKGROUP) == 0)
                    __builtin_amdgcn_s_sleep(1);
                __asm__ volatile("" ::: "memory");
                const int slot = (k + 2) & (S - 1);
                #pragma unroll
                for (int u = 0; u < U; ++u) { ai[u] = ringI[slot][u][lane]; az[u] = ringZ[slot][u][lane]; }
            }
            // compute chunk k+1 from b
            #pragma unroll
            for (int u = 0; u < U; ++u) {
                #pragma clang fp contract(off)
                float d  = bi[u] - V;
                float v1 = V + 0.05f * d;
                float v2 = v1 + bz[u];
                bool  s  = (v2 >= Vth);
                V = s ? 0.0f : v2;
                float nth = fminf(fmaxf(Vth + 0.1f, 0.5f), 2.0f);
                Vth = s ? nth : Vth;
                op[(size_t)((k + 1) * U + u) * N] = s ? 1.0f : 0.0f;
            }
            // free slots up to k+1 (publish once per pair)
            __asm__ volatile("s_waitcnt lgkmcnt(0)" ::: "memory");
            if (lane == 0)
                __hip_atomic_store(&cons, k + 1, __ATOMIC_RELAXED,
                                   __HIP_MEMORY_SCOPE_WORKGROUP);
        }
    }
}

extern "C" void kernel_launch(void* const* d_in, const int* in_sizes, int n_in,
                              void* d_out, int out_size, void* d_ws, size_t ws_size,
                              hipStream_t stream) {
    const float* input_current = (const float*)d_in[0];
    const float* noise         = (const float*)d_in[1];
    float* out                 = (float*)d_out;

    // 256 blocks x 512 threads: 1 consumer + 7 producer waves, 64 neurons/block.
    TorchLIFNeuronGroup_85152021610615_kernel<<<N / 64, 512, 0, stream>>>(
        input_current, noise, out);
}